// Round 1
// baseline (1235.037 us; speedup 1.0000x reference)
//
#include <hip/hip_runtime.h>

#define B_ 2
#define S_ 2048
#define D_ 1024
#define H_ 16
#define HD_ 64

typedef float f32x4 __attribute__((ext_vector_type(4)));
typedef short s16x8 __attribute__((ext_vector_type(8)));

#define MFMA16(a, b, c) __builtin_amdgcn_mfma_f32_16x16x32_bf16((a), (b), (c), 0, 0, 0)

__device__ __forceinline__ unsigned short bf16_rne(float f) {
    unsigned int u = __float_as_uint(f);
    u += 0x7FFFu + ((u >> 16) & 1u);
    return (unsigned short)(u >> 16);
}
__device__ __forceinline__ float bf16_f32(unsigned short h) {
    return __uint_as_float(((unsigned int)h) << 16);
}
__device__ __forceinline__ void split_bf16(float x, short& hi, short& lo) {
    unsigned short h = bf16_rne(x);
    float r = x - bf16_f32(h);
    hi = (short)h;
    lo = (short)bf16_rne(r);
}

// ---------------------------------------------------------------------------
// Kernel 1: weight transpose + split to bf16 hi/lo.  Wt[n][k] = W[k][n].
// ---------------------------------------------------------------------------
__global__ void wt_split_kernel(const float* __restrict__ W0, const float* __restrict__ W1,
                                const float* __restrict__ W2, const float* __restrict__ W3,
                                short* __restrict__ WtHi, short* __restrict__ WtLo) {
    int z = blockIdx.z;
    const float* W = (z == 0) ? W0 : (z == 1) ? W1 : (z == 2) ? W2 : W3;
    short* Hi = WtHi + (size_t)z * 1048576;
    short* Lo = WtLo + (size_t)z * 1048576;
    __shared__ float tile[32][33];
    int n0 = blockIdx.x * 32, k0 = blockIdx.y * 32;
    int c = threadIdx.x & 31, r = threadIdx.x >> 5;  // r in 0..7
#pragma unroll
    for (int i = 0; i < 4; i++) {
        int kl = r + i * 8;
        tile[kl][c] = W[(size_t)(k0 + kl) * D_ + n0 + c];
    }
    __syncthreads();
#pragma unroll
    for (int i = 0; i < 4; i++) {
        int nl = r + i * 8;
        float v = tile[c][nl];  // = W[k0+c][n0+nl]
        short h, l;
        split_bf16(v, h, l);
        size_t idx = (size_t)(n0 + nl) * D_ + k0 + c;
        Hi[idx] = h;
        Lo[idx] = l;
    }
}

// ---------------------------------------------------------------------------
// Kernel 2: QKV projection, split-bf16 GEMM. C = X @ W + b.
// 64x64 tile, BK=32, 256 threads (4 waves in 2x2), 16x16x32 MFMA, 3x split.
// z=0 -> Q (row-major), z=1 -> K (row-major), z=2 -> V transposed [B,H,HD,S].
// ---------------------------------------------------------------------------
__global__ __launch_bounds__(256) void proj_kernel(
    const float* __restrict__ Xq, const float* __restrict__ Xk, const float* __restrict__ Xv,
    const float* __restrict__ bq, const float* __restrict__ bk, const float* __restrict__ bv,
    const short* __restrict__ WtHi, const short* __restrict__ WtLo,
    short* __restrict__ Qhi, short* __restrict__ Qlo,
    short* __restrict__ Khi, short* __restrict__ Klo,
    short* __restrict__ VtHi, short* __restrict__ VtLo) {
    int z = blockIdx.z;
    const float* X = (z == 0) ? Xq : (z == 1) ? Xk : Xv;
    const float* bias = (z == 0) ? bq : (z == 1) ? bk : bv;
    const short* BH = WtHi + (size_t)z * 1048576;
    const short* BL = WtLo + (size_t)z * 1048576;
    int n0 = blockIdx.x * 64, m0 = blockIdx.y * 64;

    __shared__ alignas(16) short Ah[64][40], Al[64][40], Bh[64][40], Bl[64][40];

    int tid = threadIdx.x;
    int lane = tid & 63, w = tid >> 6;
    int wm = (w >> 1) * 32, wn = (w & 1) * 32;
    int quad = lane >> 4, l15 = lane & 15;

    f32x4 acc[2][2] = {};
    int sr = tid >> 2, scol = (tid & 3) * 8;

    for (int kb = 0; kb < 32; kb++) {
        int k0 = kb * 32;
        const float* src = X + (size_t)(m0 + sr) * D_ + k0 + scol;
        float4 f0 = *(const float4*)(src);
        float4 f1 = *(const float4*)(src + 4);
        float v[8] = {f0.x, f0.y, f0.z, f0.w, f1.x, f1.y, f1.z, f1.w};
        s16x8 hi8, lo8;
#pragma unroll
        for (int i = 0; i < 8; i++) {
            short h, l;
            split_bf16(v[i], h, l);
            hi8[i] = h;
            lo8[i] = l;
        }
        *(s16x8*)&Ah[sr][scol] = hi8;
        *(s16x8*)&Al[sr][scol] = lo8;
        *(s16x8*)&Bh[sr][scol] = *(const s16x8*)(BH + (size_t)(n0 + sr) * D_ + k0 + scol);
        *(s16x8*)&Bl[sr][scol] = *(const s16x8*)(BL + (size_t)(n0 + sr) * D_ + k0 + scol);
        __syncthreads();

        s16x8 ah[2], al[2], bh[2], bl[2];
#pragma unroll
        for (int mi = 0; mi < 2; mi++) {
            int m = wm + mi * 16 + l15;
            ah[mi] = *(const s16x8*)&Ah[m][quad * 8];
            al[mi] = *(const s16x8*)&Al[m][quad * 8];
        }
#pragma unroll
        for (int ni = 0; ni < 2; ni++) {
            int n = wn + ni * 16 + l15;
            bh[ni] = *(const s16x8*)&Bh[n][quad * 8];
            bl[ni] = *(const s16x8*)&Bl[n][quad * 8];
        }
#pragma unroll
        for (int mi = 0; mi < 2; mi++)
#pragma unroll
            for (int ni = 0; ni < 2; ni++) {
                acc[mi][ni] = MFMA16(ah[mi], bh[ni], acc[mi][ni]);
                acc[mi][ni] = MFMA16(ah[mi], bl[ni], acc[mi][ni]);
                acc[mi][ni] = MFMA16(al[mi], bh[ni], acc[mi][ni]);
            }
        __syncthreads();
    }

#pragma unroll
    for (int mi = 0; mi < 2; mi++)
#pragma unroll
        for (int ni = 0; ni < 2; ni++) {
            int nglob = n0 + wn + ni * 16 + l15;
            float bb = bias[nglob];
#pragma unroll
            for (int r = 0; r < 4; r++) {
                int mglob = m0 + wm + mi * 16 + quad * 4 + r;
                float cv = acc[mi][ni][r] + bb;
                short h, l;
                split_bf16(cv, h, l);
                if (z == 2) {
                    int bidx = mglob >> 11, s = mglob & 2047;
                    int hh = nglob >> 6, d = nglob & 63;
                    size_t idx = ((size_t)((bidx * H_ + hh) * HD_ + d)) * S_ + s;
                    VtHi[idx] = h;
                    VtLo[idx] = l;
                } else if (z == 0) {
                    size_t idx = (size_t)mglob * D_ + nglob;
                    Qhi[idx] = h;
                    Qlo[idx] = l;
                } else {
                    size_t idx = (size_t)mglob * D_ + nglob;
                    Khi[idx] = h;
                    Klo[idx] = l;
                }
            }
        }
}

// ---------------------------------------------------------------------------
// Kernel 3: attention. One block = 16 Q rows of one (b,h). 16 waves (1024
// threads), each wave owns 128 keys; 16x128 scores live in 8 f32x4 MFMA
// accumulators per wave (sc[8] = 32 regs -> total ~110 regs/lane -> 4
// waves/SIMD = 50% occupancy, vs 25% for the old sc[32] layout).
// XCD-aware block swizzle keeps one head's K/V L2-resident per XCD;
// attn output uses non-temporal stores so the 536MB stream doesn't evict K/V.
// Pbuf (P-transpose) and ctx-combine buffers are union-aliased to stay <64KB.
// ---------------------------------------------------------------------------
__global__ __launch_bounds__(1024, 4) void attn_kernel(
    const short* __restrict__ Qhi, const short* __restrict__ Qlo,
    const short* __restrict__ Khi, const short* __restrict__ Klo,
    const short* __restrict__ VtHi, const short* __restrict__ VtLo,
    float* __restrict__ attn, short* __restrict__ CtxHi, short* __restrict__ CtxLo) {
    // bijective XCD swizzle: 4096 blocks = 8 XCDs x 512. Blocks with the same
    // (lin % 8) land on the same XCD (round-robin dispatch); give each XCD a
    // contiguous chunk of (b,h,q-tile) space so concurrent blocks share K/V.
    int lin = blockIdx.x + 128 * (blockIdx.y + 16 * blockIdx.z);  // 0..4095
    int nl = (lin & 7) * 512 + (lin >> 3);
    int q0 = (nl & 127) * 16;
    int h = (nl >> 7) & 15;
    int b = nl >> 11;

    int tid = threadIdx.x, w = tid >> 6, lane = tid & 63;  // w in 0..15
    int quad = lane >> 4, l15 = lane & 15;

    __shared__ float redbuf[16][16];
    __shared__ alignas(16) union {
        short P[16][2][16][40];   // per-wave P transpose staging (40960 B)
        float ctx[8][16][64];     // paired ctx combine (32768 B)
    } sbuf;

    // Q fragments: A[m=lane&15][k=quad*8+j], two kd-chunks (0..31, 32..63)
    size_t qrow = ((size_t)(b * S_ + q0 + l15)) * D_ + h * HD_;
    s16x8 qh[2], ql[2];
    qh[0] = *(const s16x8*)(Qhi + qrow + quad * 8);
    qh[1] = *(const s16x8*)(Qhi + qrow + 32 + quad * 8);
    ql[0] = *(const s16x8*)(Qlo + qrow + quad * 8);
    ql[1] = *(const s16x8*)(Qlo + qrow + 32 + quad * 8);

    int key_base = w * 128;
    f32x4 zero4 = {0.f, 0.f, 0.f, 0.f};
    f32x4 sc[8];
#pragma unroll
    for (int t = 0; t < 8; t++) sc[t] = zero4;

    // scores: S = Q @ K^T (split, 3 MFMA per kd-chunk)
    size_t krowbase = ((size_t)(b * S_ + key_base)) * D_ + h * HD_;
#pragma unroll
    for (int kt = 0; kt < 8; kt++) {
        size_t krow = krowbase + (size_t)(kt * 16 + l15) * D_;
        s16x8 kh0 = *(const s16x8*)(Khi + krow + quad * 8);
        s16x8 kl0 = *(const s16x8*)(Klo + krow + quad * 8);
        s16x8 kh1 = *(const s16x8*)(Khi + krow + 32 + quad * 8);
        s16x8 kl1 = *(const s16x8*)(Klo + krow + 32 + quad * 8);
        f32x4 a = sc[kt];
        a = MFMA16(qh[0], kh0, a);
        a = MFMA16(qh[0], kl0, a);
        a = MFMA16(ql[0], kh0, a);
        a = MFMA16(qh[1], kh1, a);
        a = MFMA16(qh[1], kl1, a);
        a = MFMA16(ql[1], kh1, a);
        sc[kt] = a;
    }

    // scale + local row max (C layout: col=key=lane&15, row=q=quad*4+r)
    const float scale = 0.125f;  // 1/sqrt(64)
    float mx[4] = {-1e30f, -1e30f, -1e30f, -1e30f};
#pragma unroll
    for (int t = 0; t < 8; t++)
#pragma unroll
        for (int r = 0; r < 4; r++) {
            float v = sc[t][r] * scale;
            sc[t][r] = v;
            mx[r] = fmaxf(mx[r], v);
        }
#pragma unroll
    for (int d = 1; d < 16; d <<= 1)
#pragma unroll
        for (int r = 0; r < 4; r++) mx[r] = fmaxf(mx[r], __shfl_xor(mx[r], d));
    if (l15 == 0) {
#pragma unroll
        for (int r = 0; r < 4; r++) redbuf[w][quad * 4 + r] = mx[r];
    }
    __syncthreads();
#pragma unroll
    for (int r = 0; r < 4; r++) {
        int q = quad * 4 + r;
        float m = redbuf[0][q];
#pragma unroll
        for (int ww = 1; ww < 16; ww++) m = fmaxf(m, redbuf[ww][q]);
        mx[r] = m;
    }
    __syncthreads();

    // exp + local sum
    float sm[4] = {0.f, 0.f, 0.f, 0.f};
#pragma unroll
    for (int t = 0; t < 8; t++)
#pragma unroll
        for (int r = 0; r < 4; r++) {
            float p = __expf(sc[t][r] - mx[r]);
            sc[t][r] = p;
            sm[r] += p;
        }
#pragma unroll
    for (int d = 1; d < 16; d <<= 1)
#pragma unroll
        for (int r = 0; r < 4; r++) sm[r] += __shfl_xor(sm[r], d);
    if (l15 == 0) {
#pragma unroll
        for (int r = 0; r < 4; r++) redbuf[w][quad * 4 + r] = sm[r];
    }
    __syncthreads();
    float rl[4];
#pragma unroll
    for (int r = 0; r < 4; r++) {
        int q = quad * 4 + r;
        float l = 0.f;
#pragma unroll
        for (int ww = 0; ww < 16; ww++) l += redbuf[ww][q];
        rl[r] = 1.0f / l;
    }

    // normalize + write attn (fp32, non-temporal: write-once stream)
    float* attn_base = attn + ((size_t)((b * H_ + h) * S_ + q0)) * S_ + key_base;
#pragma unroll
    for (int t = 0; t < 8; t++)
#pragma unroll
        for (int r = 0; r < 4; r++) {
            float p = sc[t][r] * rl[r];
            sc[t][r] = p;
            __builtin_nontemporal_store(p, attn_base + (size_t)(quad * 4 + r) * S_ + t * 16 + l15);
        }

    // PV: ctx = P @ V  (P transposed into A-frag layout via wave-local LDS)
    f32x4 cacc[4];
#pragma unroll
    for (int nt = 0; nt < 4; nt++) cacc[nt] = zero4;
    size_t vbase = ((size_t)((b * H_ + h) * HD_)) * S_ + key_base;
#pragma unroll
    for (int c = 0; c < 4; c++) {  // 32-key chunks
#pragma unroll
        for (int tt = 0; tt < 2; tt++) {
#pragma unroll
            for (int r = 0; r < 4; r++) {
                float p = sc[2 * c + tt][r];
                short ph, pl;
                split_bf16(p, ph, pl);
                sbuf.P[w][0][quad * 4 + r][tt * 16 + l15] = ph;
                sbuf.P[w][1][quad * 4 + r][tt * 16 + l15] = pl;
            }
        }
        // wave-local LDS RAW: DS ops from one wave execute in order; compiler waits
        s16x8 pa_h = *(const s16x8*)&sbuf.P[w][0][l15][quad * 8];
        s16x8 pa_l = *(const s16x8*)&sbuf.P[w][1][l15][quad * 8];
#pragma unroll
        for (int nt = 0; nt < 4; nt++) {
            size_t vrow = vbase + (size_t)(nt * 16 + l15) * S_ + c * 32;
            s16x8 vh = *(const s16x8*)(VtHi + vrow + quad * 8);
            s16x8 vl = *(const s16x8*)(VtLo + vrow + quad * 8);
            f32x4 a = cacc[nt];
            a = MFMA16(pa_h, vh, a);
            a = MFMA16(pa_h, vl, a);
            a = MFMA16(pa_l, vh, a);
            cacc[nt] = a;
        }
    }

    // combine partial ctx across 16 waves: pair (w, w+8) first, then 8-way.
    __syncthreads();  // all Pbuf reads done before ctx aliases it
    if (w >= 8) {
#pragma unroll
        for (int nt = 0; nt < 4; nt++)
#pragma unroll
            for (int r = 0; r < 4; r++) sbuf.ctx[w - 8][quad * 4 + r][nt * 16 + l15] = cacc[nt][r];
    }
    __syncthreads();
    if (w < 8) {
#pragma unroll
        for (int nt = 0; nt < 4; nt++)
#pragma unroll
            for (int r = 0; r < 4; r++) sbuf.ctx[w][quad * 4 + r][nt * 16 + l15] += cacc[nt][r];
    }
    __syncthreads();
    {
        int q = tid >> 6, d = tid & 63;  // 1024 threads cover [16 q][64 d]
        float cv = 0.f;
#pragma unroll
        for (int ww = 0; ww < 8; ww++) cv += sbuf.ctx[ww][q][d];
        short hh, ll;
        split_bf16(cv, hh, ll);
        size_t cidx = (size_t)(b * S_ + q0 + q) * D_ + h * HD_ + d;
        CtxHi[cidx] = hh;
        CtxLo[cidx] = ll;
    }
}

// ---------------------------------------------------------------------------
// Kernel 4: out projection. out = Ctx @ Wo + bo (fp32 result to d_out).
// ---------------------------------------------------------------------------
__global__ __launch_bounds__(256) void oproj_kernel(
    const short* __restrict__ CtxHi, const short* __restrict__ CtxLo,
    const short* __restrict__ WtHi, const short* __restrict__ WtLo,
    const float* __restrict__ bo, float* __restrict__ out) {
    const short* BH = WtHi + (size_t)3 * 1048576;
    const short* BL = WtLo + (size_t)3 * 1048576;
    int n0 = blockIdx.x * 64, m0 = blockIdx.y * 64;
    __shared__ alignas(16) short Ah[64][40], Al[64][40], Bh[64][40], Bl[64][40];
    int tid = threadIdx.x;
    int lane = tid & 63, w = tid >> 6;
    int wm = (w >> 1) * 32, wn = (w & 1) * 32;
    int quad = lane >> 4, l15 = lane & 15;
    f32x4 acc[2][2] = {};
    int sr = tid >> 2, scol = (tid & 3) * 8;

    for (int kb = 0; kb < 32; kb++) {
        int k0 = kb * 32;
        *(s16x8*)&Ah[sr][scol] = *(const s16x8*)(CtxHi + (size_t)(m0 + sr) * D_ + k0 + scol);
        *(s16x8*)&Al[sr][scol] = *(const s16x8*)(CtxLo + (size_t)(m0 + sr) * D_ + k0 + scol);
        *(s16x8*)&Bh[sr][scol] = *(const s16x8*)(BH + (size_t)(n0 + sr) * D_ + k0 + scol);
        *(s16x8*)&Bl[sr][scol] = *(const s16x8*)(BL + (size_t)(n0 + sr) * D_ + k0 + scol);
        __syncthreads();
        s16x8 ah[2], al[2], bh[2], bl[2];
#pragma unroll
        for (int mi = 0; mi < 2; mi++) {
            int m = wm + mi * 16 + l15;
            ah[mi] = *(const s16x8*)&Ah[m][quad * 8];
            al[mi] = *(const s16x8*)&Al[m][quad * 8];
        }
#pragma unroll
        for (int ni = 0; ni < 2; ni++) {
            int n = wn + ni * 16 + l15;
            bh[ni] = *(const s16x8*)&Bh[n][quad * 8];
            bl[ni] = *(const s16x8*)&Bl[n][quad * 8];
        }
#pragma unroll
        for (int mi = 0; mi < 2; mi++)
#pragma unroll
            for (int ni = 0; ni < 2; ni++) {
                acc[mi][ni] = MFMA16(ah[mi], bh[ni], acc[mi][ni]);
                acc[mi][ni] = MFMA16(ah[mi], bl[ni], acc[mi][ni]);
                acc[mi][ni] = MFMA16(al[mi], bh[ni], acc[mi][ni]);
            }
        __syncthreads();
    }
#pragma unroll
    for (int mi = 0; mi < 2; mi++)
#pragma unroll
        for (int ni = 0; ni < 2; ni++) {
            int nglob = n0 + wn + ni * 16 + l15;
            float bb = bo[nglob];
#pragma unroll
            for (int r = 0; r < 4; r++) {
                int mglob = m0 + wm + mi * 16 + quad * 4 + r;
                out[(size_t)mglob * D_ + nglob] = acc[mi][ni][r] + bb;
            }
        }
}

// ---------------------------------------------------------------------------
extern "C" void kernel_launch(void* const* d_in, const int* in_sizes, int n_in,
                              void* d_out, int out_size, void* d_ws, size_t ws_size,
                              hipStream_t stream) {
    const float* q_in = (const float*)d_in[0];
    const float* k_in = (const float*)d_in[1];
    const float* v_in = (const float*)d_in[2];
    const float* Wq = (const float*)d_in[3];
    const float* bq = (const float*)d_in[4];
    const float* Wk = (const float*)d_in[5];
    const float* bk = (const float*)d_in[6];
    const float* Wv = (const float*)d_in[7];
    const float* bv = (const float*)d_in[8];
    const float* Wo = (const float*)d_in[9];
    const float* bo = (const float*)d_in[10];

    // ws layout: 10 buffers x 8 MiB = 80 MiB of split-bf16 intermediates
    char* ws = (char*)d_ws;
    const size_t MB8 = 8u * 1024u * 1024u;
    short* WtHi = (short*)(ws + 0 * MB8);   // [4][1024][1024] (q,k,v,o), transposed
    short* WtLo = (short*)(ws + 1 * MB8);
    short* Qhi = (short*)(ws + 2 * MB8);    // [4096][1024]
    short* Qlo = (short*)(ws + 3 * MB8);
    short* Khi = (short*)(ws + 4 * MB8);    // [4096][1024]
    short* Klo = (short*)(ws + 5 * MB8);
    short* VtHi = (short*)(ws + 6 * MB8);   // [B][H][64][2048]
    short* VtLo = (short*)(ws + 7 * MB8);
    short* CtxHi = (short*)(ws + 8 * MB8);  // [4096][1024]
    short* CtxLo = (short*)(ws + 9 * MB8);

    float* out = (float*)d_out;                    // [2][2048][1024]
    float* attn = out + (size_t)B_ * S_ * D_;      // [2][16][2048][2048]

    wt_split_kernel<<<dim3(32, 32, 4), 256, 0, stream>>>(Wq, Wk, Wv, Wo, WtHi, WtLo);
    proj_kernel<<<dim3(16, 64, 3), 256, 0, stream>>>(q_in, k_in, v_in, bq, bk, bv,
                                                     WtHi, WtLo, Qhi, Qlo, Khi, Klo, VtHi, VtLo);
    attn_kernel<<<dim3(128, 16, 2), 1024, 0, stream>>>(Qhi, Qlo, Khi, Klo, VtHi, VtLo,
                                                       attn, CtxHi, CtxLo);
    oproj_kernel<<<dim3(16, 64), 256, 0, stream>>>(CtxHi, CtxLo, WtHi, WtLo, bo, out);
}

// Round 3
// 1198.660 us; speedup vs baseline: 1.0303x; 1.0303x over previous
//
#include <hip/hip_runtime.h>

#define B_ 2
#define S_ 2048
#define D_ 1024
#define H_ 16
#define HD_ 64

typedef float f32x4 __attribute__((ext_vector_type(4)));
typedef short s16x8 __attribute__((ext_vector_type(8)));
typedef short s16x4 __attribute__((ext_vector_type(4)));

#define MFMA16(a, b, c) __builtin_amdgcn_mfma_f32_16x16x32_bf16((a), (b), (c), 0, 0, 0)

__device__ __forceinline__ unsigned short bf16_rne(float f) {
    unsigned int u = __float_as_uint(f);
    u += 0x7FFFu + ((u >> 16) & 1u);
    return (unsigned short)(u >> 16);
}
__device__ __forceinline__ float bf16_f32(unsigned short h) {
    return __uint_as_float(((unsigned int)h) << 16);
}
__device__ __forceinline__ void split_bf16(float x, short& hi, short& lo) {
    unsigned short h = bf16_rne(x);
    float r = x - bf16_f32(h);
    hi = (short)h;
    lo = (short)bf16_rne(r);
}

// ---------------------------------------------------------------------------
// Kernel 1: weight transpose + split to bf16 hi/lo.  Wt[n][k] = W[k][n].
// ---------------------------------------------------------------------------
__global__ void wt_split_kernel(const float* __restrict__ W0, const float* __restrict__ W1,
                                const float* __restrict__ W2, const float* __restrict__ W3,
                                short* __restrict__ WtHi, short* __restrict__ WtLo) {
    int z = blockIdx.z;
    const float* W = (z == 0) ? W0 : (z == 1) ? W1 : (z == 2) ? W2 : W3;
    short* Hi = WtHi + (size_t)z * 1048576;
    short* Lo = WtLo + (size_t)z * 1048576;
    __shared__ float tile[32][33];
    int n0 = blockIdx.x * 32, k0 = blockIdx.y * 32;
    int c = threadIdx.x & 31, r = threadIdx.x >> 5;  // r in 0..7
#pragma unroll
    for (int i = 0; i < 4; i++) {
        int kl = r + i * 8;
        tile[kl][c] = W[(size_t)(k0 + kl) * D_ + n0 + c];
    }
    __syncthreads();
#pragma unroll
    for (int i = 0; i < 4; i++) {
        int nl = r + i * 8;
        float v = tile[c][nl];  // = W[k0+c][n0+nl]
        short h, l;
        split_bf16(v, h, l);
        size_t idx = (size_t)(n0 + nl) * D_ + k0 + c;
        Hi[idx] = h;
        Lo[idx] = l;
    }
}

// ---------------------------------------------------------------------------
// Kernel 2: QKV projection, split-bf16 GEMM. C = X @ W + b.
// 64x64 tile, BK=32, 256 threads (4 waves in 2x2), 16x16x32 MFMA, 3x split.
// z=0 -> Q (row-major), z=1 -> K (row-major), z=2 -> V transposed [B,H,HD,S].
// ---------------------------------------------------------------------------
__global__ __launch_bounds__(256) void proj_kernel(
    const float* __restrict__ Xq, const float* __restrict__ Xk, const float* __restrict__ Xv,
    const float* __restrict__ bq, const float* __restrict__ bk, const float* __restrict__ bv,
    const short* __restrict__ WtHi, const short* __restrict__ WtLo,
    short* __restrict__ Qhi, short* __restrict__ Qlo,
    short* __restrict__ Khi, short* __restrict__ Klo,
    short* __restrict__ VtHi, short* __restrict__ VtLo) {
    int z = blockIdx.z;
    const float* X = (z == 0) ? Xq : (z == 1) ? Xk : Xv;
    const float* bias = (z == 0) ? bq : (z == 1) ? bk : bv;
    const short* BH = WtHi + (size_t)z * 1048576;
    const short* BL = WtLo + (size_t)z * 1048576;
    int n0 = blockIdx.x * 64, m0 = blockIdx.y * 64;

    __shared__ alignas(16) short Ah[64][40], Al[64][40], Bh[64][40], Bl[64][40];

    int tid = threadIdx.x;
    int lane = tid & 63, w = tid >> 6;
    int wm = (w >> 1) * 32, wn = (w & 1) * 32;
    int quad = lane >> 4, l15 = lane & 15;

    f32x4 acc[2][2] = {};
    int sr = tid >> 2, scol = (tid & 3) * 8;

    for (int kb = 0; kb < 32; kb++) {
        int k0 = kb * 32;
        const float* src = X + (size_t)(m0 + sr) * D_ + k0 + scol;
        float4 f0 = *(const float4*)(src);
        float4 f1 = *(const float4*)(src + 4);
        float v[8] = {f0.x, f0.y, f0.z, f0.w, f1.x, f1.y, f1.z, f1.w};
        s16x8 hi8, lo8;
#pragma unroll
        for (int i = 0; i < 8; i++) {
            short h, l;
            split_bf16(v[i], h, l);
            hi8[i] = h;
            lo8[i] = l;
        }
        *(s16x8*)&Ah[sr][scol] = hi8;
        *(s16x8*)&Al[sr][scol] = lo8;
        *(s16x8*)&Bh[sr][scol] = *(const s16x8*)(BH + (size_t)(n0 + sr) * D_ + k0 + scol);
        *(s16x8*)&Bl[sr][scol] = *(const s16x8*)(BL + (size_t)(n0 + sr) * D_ + k0 + scol);
        __syncthreads();

        s16x8 ah[2], al[2], bh[2], bl[2];
#pragma unroll
        for (int mi = 0; mi < 2; mi++) {
            int m = wm + mi * 16 + l15;
            ah[mi] = *(const s16x8*)&Ah[m][quad * 8];
            al[mi] = *(const s16x8*)&Al[m][quad * 8];
        }
#pragma unroll
        for (int ni = 0; ni < 2; ni++) {
            int n = wn + ni * 16 + l15;
            bh[ni] = *(const s16x8*)&Bh[n][quad * 8];
            bl[ni] = *(const s16x8*)&Bl[n][quad * 8];
        }
#pragma unroll
        for (int mi = 0; mi < 2; mi++)
#pragma unroll
            for (int ni = 0; ni < 2; ni++) {
                acc[mi][ni] = MFMA16(ah[mi], bh[ni], acc[mi][ni]);
                acc[mi][ni] = MFMA16(ah[mi], bl[ni], acc[mi][ni]);
                acc[mi][ni] = MFMA16(al[mi], bh[ni], acc[mi][ni]);
            }
        __syncthreads();
    }

#pragma unroll
    for (int mi = 0; mi < 2; mi++)
#pragma unroll
        for (int ni = 0; ni < 2; ni++) {
            int nglob = n0 + wn + ni * 16 + l15;
            float bb = bias[nglob];
#pragma unroll
            for (int r = 0; r < 4; r++) {
                int mglob = m0 + wm + mi * 16 + quad * 4 + r;
                float cv = acc[mi][ni][r] + bb;
                short h, l;
                split_bf16(cv, h, l);
                if (z == 2) {
                    int bidx = mglob >> 11, s = mglob & 2047;
                    int hh = nglob >> 6, d = nglob & 63;
                    size_t idx = ((size_t)((bidx * H_ + hh) * HD_ + d)) * S_ + s;
                    VtHi[idx] = h;
                    VtLo[idx] = l;
                } else if (z == 0) {
                    size_t idx = (size_t)mglob * D_ + nglob;
                    Qhi[idx] = h;
                    Qlo[idx] = l;
                } else {
                    size_t idx = (size_t)mglob * D_ + nglob;
                    Khi[idx] = h;
                    Klo[idx] = l;
                }
            }
        }
}

// ---------------------------------------------------------------------------
// Kernel 3: attention. One block = 16 Q rows of one (b,h). 4 waves, each owns
// 512 keys; scores computed SWAPPED: mfma(K, Q) -> frag [key][q] with
// col=lane&15=q, row=quad*4+r=key. Key axis is lane-local:
//   - softmax reduce = 127 reg ops + shfl_xor(16) + shfl_xor(32)
//   - attn store = f32x4 (4 consecutive keys per lane), 32 insts/wave
//   - P staging for PV = packed short4 LDS writes
// XCD-aware swizzle keeps one head's K/V L2-resident per XCD (FETCH 140->25MB
// measured). No nontemporal stores (measured +27% WRITE_SIZE amplification).
// ---------------------------------------------------------------------------
__global__ __launch_bounds__(256, 2) void attn_kernel(
    const short* __restrict__ Qhi, const short* __restrict__ Qlo,
    const short* __restrict__ Khi, const short* __restrict__ Klo,
    const short* __restrict__ VtHi, const short* __restrict__ VtLo,
    float* __restrict__ attn, short* __restrict__ CtxHi, short* __restrict__ CtxLo) {
    // bijective XCD swizzle: 4096 blocks = 8 XCDs x 512. Blocks with equal
    // (lin % 8) land on one XCD; give each XCD a contiguous (b,h,q0) chunk.
    int lin = blockIdx.x + 128 * (blockIdx.y + 16 * blockIdx.z);  // 0..4095
    int nl = (lin & 7) * 512 + (lin >> 3);
    int q0 = (nl & 127) * 16;
    int h = (nl >> 7) & 15;
    int b = nl >> 11;

    int tid = threadIdx.x, w = tid >> 6, lane = tid & 63;
    int quad = lane >> 4, l15 = lane & 15;

    __shared__ float redmax[4][16];
    __shared__ float redsum[4][16];
    __shared__ float ctxbuf[4][16][64];
    __shared__ alignas(16) short Pbuf[4][2][16][40];

    // Q fragments (B operand): B[n=q=l15][k=quad*8+j], two kd-chunks
    size_t qrow = ((size_t)(b * S_ + q0 + l15)) * D_ + h * HD_;
    s16x8 qh[2], ql[2];
    qh[0] = *(const s16x8*)(Qhi + qrow + quad * 8);
    qh[1] = *(const s16x8*)(Qhi + qrow + 32 + quad * 8);
    ql[0] = *(const s16x8*)(Qlo + qrow + quad * 8);
    ql[1] = *(const s16x8*)(Qlo + qrow + 32 + quad * 8);

    int key_base = w * 512;
    f32x4 zero4 = {0.f, 0.f, 0.f, 0.f};
    f32x4 sc[32];
#pragma unroll
    for (int t = 0; t < 32; t++) sc[t] = zero4;

    // scores SWAPPED: sc[t][r] = S[key=key_base+t*16+quad*4+r][q=q0+l15]
    size_t krowbase = ((size_t)(b * S_ + key_base)) * D_ + h * HD_;
#pragma unroll
    for (int kt = 0; kt < 32; kt++) {
        size_t krow = krowbase + (size_t)(kt * 16 + l15) * D_;
        s16x8 kh0 = *(const s16x8*)(Khi + krow + quad * 8);
        s16x8 kl0 = *(const s16x8*)(Klo + krow + quad * 8);
        s16x8 kh1 = *(const s16x8*)(Khi + krow + 32 + quad * 8);
        s16x8 kl1 = *(const s16x8*)(Klo + krow + 32 + quad * 8);
        f32x4 a = sc[kt];
        a = MFMA16(kh0, qh[0], a);
        a = MFMA16(kl0, qh[0], a);
        a = MFMA16(kh0, ql[0], a);
        a = MFMA16(kh1, qh[1], a);
        a = MFMA16(kl1, qh[1], a);
        a = MFMA16(kh1, ql[1], a);
        sc[kt] = a;
    }

    // scale + max over this wave's 512 keys for q=l15 (lane-local + 2 shuffles)
    const float scale = 0.125f;  // 1/sqrt(64)
    float mx = -1e30f;
#pragma unroll
    for (int t = 0; t < 32; t++)
#pragma unroll
        for (int r = 0; r < 4; r++) {
            float v = sc[t][r] * scale;
            sc[t][r] = v;
            mx = fmaxf(mx, v);
        }
    mx = fmaxf(mx, __shfl_xor(mx, 16));
    mx = fmaxf(mx, __shfl_xor(mx, 32));
    if (lane < 16) redmax[w][lane] = mx;
    __syncthreads();
    mx = fmaxf(fmaxf(redmax[0][l15], redmax[1][l15]),
               fmaxf(redmax[2][l15], redmax[3][l15]));

    // exp + sum
    float sm = 0.f;
#pragma unroll
    for (int t = 0; t < 32; t++)
#pragma unroll
        for (int r = 0; r < 4; r++) {
            float p = __expf(sc[t][r] - mx);
            sc[t][r] = p;
            sm += p;
        }
    sm += __shfl_xor(sm, 16);
    sm += __shfl_xor(sm, 32);
    if (lane < 16) redsum[w][lane] = sm;
    __syncthreads();
    float rl = 1.0f / (redsum[0][l15] + redsum[1][l15] + redsum[2][l15] + redsum[3][l15]);

    // normalize + write attn: lane holds 4 consecutive keys of row q=l15 -> f32x4
    float* attn_base = attn + ((size_t)((b * H_ + h) * S_ + q0)) * S_ + key_base;
#pragma unroll
    for (int t = 0; t < 32; t++) {
        f32x4 p4 = sc[t] * rl;
        sc[t] = p4;
        *(f32x4*)(attn_base + (size_t)l15 * S_ + t * 16 + quad * 4) = p4;
    }

    // PV: ctx = P @ V. P already [key][q]-local: pack 4 keys -> short4 LDS write,
    // read back as A-frag A[m=q=l15][k=quad*8+j].
    f32x4 cacc[4];
#pragma unroll
    for (int nt = 0; nt < 4; nt++) cacc[nt] = zero4;
    size_t vbase = ((size_t)((b * H_ + h) * HD_)) * S_ + key_base;
#pragma unroll
    for (int c = 0; c < 16; c++) {  // 32-key chunks
#pragma unroll
        for (int tt = 0; tt < 2; tt++) {
            f32x4 p4 = sc[2 * c + tt];
            s16x4 h4, l4;
#pragma unroll
            for (int r = 0; r < 4; r++) {
                short ph, pl;
                split_bf16(p4[r], ph, pl);
                h4[r] = ph;
                l4[r] = pl;
            }
            *(s16x4*)&Pbuf[w][0][l15][tt * 16 + quad * 4] = h4;
            *(s16x4*)&Pbuf[w][1][l15][tt * 16 + quad * 4] = l4;
        }
        // wave-local LDS RAW: DS ops from one wave execute in order; compiler waits
        s16x8 pa_h = *(const s16x8*)&Pbuf[w][0][l15][quad * 8];
        s16x8 pa_l = *(const s16x8*)&Pbuf[w][1][l15][quad * 8];
#pragma unroll
        for (int nt = 0; nt < 4; nt++) {
            size_t vrow = vbase + (size_t)(nt * 16 + l15) * S_ + c * 32;
            s16x8 vh = *(const s16x8*)(VtHi + vrow + quad * 8);
            s16x8 vl = *(const s16x8*)(VtLo + vrow + quad * 8);
            f32x4 a = cacc[nt];
            a = MFMA16(pa_h, vh, a);
            a = MFMA16(pa_h, vl, a);
            a = MFMA16(pa_l, vh, a);
            cacc[nt] = a;
        }
    }

    // combine partial ctx across waves
#pragma unroll
    for (int nt = 0; nt < 4; nt++)
#pragma unroll
        for (int r = 0; r < 4; r++) ctxbuf[w][quad * 4 + r][nt * 16 + l15] = cacc[nt][r];
    __syncthreads();
#pragma unroll
    for (int i = 0; i < 4; i++) {
        int idx = tid + i * 256;  // 0..1023 over [16 q][64 d]
        int q = idx >> 6, d = idx & 63;
        float cv = ctxbuf[0][q][d] + ctxbuf[1][q][d] + ctxbuf[2][q][d] + ctxbuf[3][q][d];
        short hh, ll;
        split_bf16(cv, hh, ll);
        size_t cidx = (size_t)(b * S_ + q0 + q) * D_ + h * HD_ + d;
        CtxHi[cidx] = hh;
        CtxLo[cidx] = ll;
    }
}

// ---------------------------------------------------------------------------
// Kernel 4: out projection. out = Ctx @ Wo + bo (fp32 result to d_out).
// ---------------------------------------------------------------------------
__global__ __launch_bounds__(256) void oproj_kernel(
    const short* __restrict__ CtxHi, const short* __restrict__ CtxLo,
    const short* __restrict__ WtHi, const short* __restrict__ WtLo,
    const float* __restrict__ bo, float* __restrict__ out) {
    const short* BH = WtHi + (size_t)3 * 1048576;
    const short* BL = WtLo + (size_t)3 * 1048576;
    int n0 = blockIdx.x * 64, m0 = blockIdx.y * 64;
    __shared__ alignas(16) short Ah[64][40], Al[64][40], Bh[64][40], Bl[64][40];
    int tid = threadIdx.x;
    int lane = tid & 63, w = tid >> 6;
    int wm = (w >> 1) * 32, wn = (w & 1) * 32;
    int quad = lane >> 4, l15 = lane & 15;
    f32x4 acc[2][2] = {};
    int sr = tid >> 2, scol = (tid & 3) * 8;

    for (int kb = 0; kb < 32; kb++) {
        int k0 = kb * 32;
        *(s16x8*)&Ah[sr][scol] = *(const s16x8*)(CtxHi + (size_t)(m0 + sr) * D_ + k0 + scol);
        *(s16x8*)&Al[sr][scol] = *(const s16x8*)(CtxLo + (size_t)(m0 + sr) * D_ + k0 + scol);
        *(s16x8*)&Bh[sr][scol] = *(const s16x8*)(BH + (size_t)(n0 + sr) * D_ + k0 + scol);
        *(s16x8*)&Bl[sr][scol] = *(const s16x8*)(BL + (size_t)(n0 + sr) * D_ + k0 + scol);
        __syncthreads();
        s16x8 ah[2], al[2], bh[2], bl[2];
#pragma unroll
        for (int mi = 0; mi < 2; mi++) {
            int m = wm + mi * 16 + l15;
            ah[mi] = *(const s16x8*)&Ah[m][quad * 8];
            al[mi] = *(const s16x8*)&Al[m][quad * 8];
        }
#pragma unroll
        for (int ni = 0; ni < 2; ni++) {
            int n = wn + ni * 16 + l15;
            bh[ni] = *(const s16x8*)&Bh[n][quad * 8];
            bl[ni] = *(const s16x8*)&Bl[n][quad * 8];
        }
#pragma unroll
        for (int mi = 0; mi < 2; mi++)
#pragma unroll
            for (int ni = 0; ni < 2; ni++) {
                acc[mi][ni] = MFMA16(ah[mi], bh[ni], acc[mi][ni]);
                acc[mi][ni] = MFMA16(ah[mi], bl[ni], acc[mi][ni]);
                acc[mi][ni] = MFMA16(al[mi], bh[ni], acc[mi][ni]);
            }
        __syncthreads();
    }
#pragma unroll
    for (int mi = 0; mi < 2; mi++)
#pragma unroll
        for (int ni = 0; ni < 2; ni++) {
            int nglob = n0 + wn + ni * 16 + l15;
            float bb = bo[nglob];
#pragma unroll
            for (int r = 0; r < 4; r++) {
                int mglob = m0 + wm + mi * 16 + quad * 4 + r;
                out[(size_t)mglob * D_ + nglob] = acc[mi][ni][r] + bb;
            }
        }
}

// ---------------------------------------------------------------------------
extern "C" void kernel_launch(void* const* d_in, const int* in_sizes, int n_in,
                              void* d_out, int out_size, void* d_ws, size_t ws_size,
                              hipStream_t stream) {
    const float* q_in = (const float*)d_in[0];
    const float* k_in = (const float*)d_in[1];
    const float* v_in = (const float*)d_in[2];
    const float* Wq = (const float*)d_in[3];
    const float* bq = (const float*)d_in[4];
    const float* Wk = (const float*)d_in[5];
    const float* bk = (const float*)d_in[6];
    const float* Wv = (const float*)d_in[7];
    const float* bv = (const float*)d_in[8];
    const float* Wo = (const float*)d_in[9];
    const float* bo = (const float*)d_in[10];

    // ws layout: 10 buffers x 8 MiB = 80 MiB of split-bf16 intermediates
    char* ws = (char*)d_ws;
    const size_t MB8 = 8u * 1024u * 1024u;
    short* WtHi = (short*)(ws + 0 * MB8);   // [4][1024][1024] (q,k,v,o), transposed
    short* WtLo = (short*)(ws + 1 * MB8);
    short* Qhi = (short*)(ws + 2 * MB8);    // [4096][1024]
    short* Qlo = (short*)(ws + 3 * MB8);
    short* Khi = (short*)(ws + 4 * MB8);    // [4096][1024]
    short* Klo = (short*)(ws + 5 * MB8);
    short* VtHi = (short*)(ws + 6 * MB8);   // [B][H][64][2048]
    short* VtLo = (short*)(ws + 7 * MB8);
    short* CtxHi = (short*)(ws + 8 * MB8);  // [4096][1024]
    short* CtxLo = (short*)(ws + 9 * MB8);

    float* out = (float*)d_out;                    // [2][2048][1024]
    float* attn = out + (size_t)B_ * S_ * D_;      // [2][16][2048][2048]

    wt_split_kernel<<<dim3(32, 32, 4), 256, 0, stream>>>(Wq, Wk, Wv, Wo, WtHi, WtLo);
    proj_kernel<<<dim3(16, 64, 3), 256, 0, stream>>>(q_in, k_in, v_in, bq, bk, bv,
                                                     WtHi, WtLo, Qhi, Qlo, Khi, Klo, VtHi, VtLo);
    attn_kernel<<<dim3(128, 16, 2), 256, 0, stream>>>(Qhi, Qlo, Khi, Klo, VtHi, VtLo,
                                                      attn, CtxHi, CtxLo);
    oproj_kernel<<<dim3(16, 64), 256, 0, stream>>>(CtxHi, CtxLo, WtHi, WtLo, bo, out);
}